// Round 3
// baseline (689.307 us; speedup 1.0000x reference)
//
#include <hip/hip_runtime.h>

// Butterfly (untied, increasing stride), batch=32768, n=1024, m=10 stages, nstack=1.
// One wave owns B_ROWS=4 rows in registers as 2 float2 row-pairs (v[2][16] = 64 VGPRs).
// Element->lane layout: e = r*256 + lane*4 + j  (r=0..3, j=0..3; 16 floats/lane/row).
//   strides 1,2    : intra-lane, position xor 1,2 (j bits)   -> float4 twiddle per pair
//   strides 4..128 : cross-lane, __shfl_xor masks 1,2,4,8,16,32 -> float2 twiddle per pos
//   strides 256,512: intra-lane, position xor 4,8 (r bits)   -> float4 twiddle per pair
//
// CRITICAL: stages are templated (compile-time STAGE) so every v[] index is a
// static constant — round 1/2 showed the unroller bailing on a runtime stage
// loop, turning v[] into dynamically-indexed memory (spill-bound, 1 GB write).

constexpr int N = 1024;
constexpr int B_ROWS = 4;   // rows per wave
constexpr int WAVES = 4;    // waves per block (block = 256 threads)

template<int STAGE>
__device__ __forceinline__ void do_stage(float2 (&v)[2][16],
                                         const float* __restrict__ tw,
                                         const int lane)
{
    constexpr int s = 1 << STAGE;
    const float* tws = tw + (STAGE << 11);   // 512*4 floats per stage

    if constexpr (s >= 4 && s <= 128) {
        // cross-lane: partner is lane ^ (s>>2)
        constexpr int m = s >> 2;
        #pragma unroll
        for (int p = 0; p < 16; ++p) {
            const int e  = ((p >> 2) << 8) | (lane << 2) | (p & 3);
            const int i  = (e >> STAGE) & 1;
            const int pr = ((e >> (STAGE + 1)) << STAGE) | (e & (s - 1));
            const float2 tt = *(const float2*)(tws + pr * 4 + i * 2); // (t[i][0], t[i][1])
            const float tA = i ? tt.y : tt.x;   // t[i][i]
            const float tB = i ? tt.x : tt.y;   // t[i][1-i]
            #pragma unroll
            for (int q = 0; q < 2; ++q) {
                const float px = __shfl_xor(v[q][p].x, m, 64);
                const float py = __shfl_xor(v[q][p].y, m, 64);
                v[q][p].x = tA * v[q][p].x + tB * px;
                v[q][p].y = tA * v[q][p].y + tB * py;
            }
        }
    } else {
        // intra-lane: pair (p, p|pm); lower element has bit STAGE == 0
        constexpr int pm = (s == 1) ? 1 : (s == 2) ? 2 : (s == 256) ? 4 : 8;
        #pragma unroll
        for (int p = 0; p < 16; ++p) {
            if constexpr (true) { if (p & pm) continue; }
            const int p2 = p | pm;
            const int e  = ((p >> 2) << 8) | (lane << 2) | (p & 3);  // i==0 element
            const int pr = ((e >> (STAGE + 1)) << STAGE) | (e & (s - 1));
            const float4 t4 = *(const float4*)(tws + pr * 4); // t00 t01 t10 t11
            #pragma unroll
            for (int q = 0; q < 2; ++q) {
                const float2 a = v[q][p];
                const float2 b = v[q][p2];
                v[q][p].x  = t4.x * a.x + t4.y * b.x;
                v[q][p].y  = t4.x * a.y + t4.y * b.y;
                v[q][p2].x = t4.z * a.x + t4.w * b.x;
                v[q][p2].y = t4.z * a.y + t4.w * b.y;
            }
        }
    }
}

__global__ __launch_bounds__(256, 4)
void butterfly_kernel(const float* __restrict__ x,
                      const float* __restrict__ tw,    // [10][512][2][2]
                      const float* __restrict__ bias,  // [1024]
                      float* __restrict__ out)
{
    const int lane  = threadIdx.x & 63;
    const int waveg = blockIdx.x * WAVES + (threadIdx.x >> 6);
    const size_t row0 = (size_t)waveg * B_ROWS;

    float2 v[2][16];   // [row-pair q][position p], .x = row 2q, .y = row 2q+1

    // ---- load: coalesced float4 per row ----
    #pragma unroll
    for (int q = 0; q < 2; ++q) {
        const float* p0 = x + (row0 + 2 * q) * N + lane * 4;
        const float* p1 = p0 + N;
        #pragma unroll
        for (int r = 0; r < 4; ++r) {
            const float4 a = *(const float4*)(p0 + r * 256);
            const float4 b = *(const float4*)(p1 + r * 256);
            v[q][r * 4 + 0] = make_float2(a.x, b.x);
            v[q][r * 4 + 1] = make_float2(a.y, b.y);
            v[q][r * 4 + 2] = make_float2(a.z, b.z);
            v[q][r * 4 + 3] = make_float2(a.w, b.w);
        }
    }

    // ---- 10 butterfly stages, fully static ----
    do_stage<0>(v, tw, lane);
    do_stage<1>(v, tw, lane);
    do_stage<2>(v, tw, lane);
    do_stage<3>(v, tw, lane);
    do_stage<4>(v, tw, lane);
    do_stage<5>(v, tw, lane);
    do_stage<6>(v, tw, lane);
    do_stage<7>(v, tw, lane);
    do_stage<8>(v, tw, lane);
    do_stage<9>(v, tw, lane);

    // ---- store with bias ----
    #pragma unroll
    for (int q = 0; q < 2; ++q) {
        float* o0 = out + (row0 + 2 * q) * N + lane * 4;
        float* o1 = o0 + N;
        #pragma unroll
        for (int r = 0; r < 4; ++r) {
            const float4 bb = *(const float4*)(bias + r * 256 + lane * 4);
            float4 a, b;
            a.x = v[q][r * 4 + 0].x + bb.x;  b.x = v[q][r * 4 + 0].y + bb.x;
            a.y = v[q][r * 4 + 1].x + bb.y;  b.y = v[q][r * 4 + 1].y + bb.y;
            a.z = v[q][r * 4 + 2].x + bb.z;  b.z = v[q][r * 4 + 2].y + bb.z;
            a.w = v[q][r * 4 + 3].x + bb.w;  b.w = v[q][r * 4 + 3].y + bb.w;
            *(float4*)(o0 + r * 256) = a;
            *(float4*)(o1 + r * 256) = b;
        }
    }
}

extern "C" void kernel_launch(void* const* d_in, const int* in_sizes, int n_in,
                              void* d_out, int out_size, void* d_ws, size_t ws_size,
                              hipStream_t stream) {
    const float* x    = (const float*)d_in[0];   // [batch][1024]
    const float* tw   = (const float*)d_in[1];   // [1][10][512][2][2]
    const float* bias = (const float*)d_in[2];   // [1024]
    float* out        = (float*)d_out;

    const int batch = in_sizes[0] / N;           // 32768
    const int blocks = batch / (B_ROWS * WAVES); // 2048
    hipLaunchKernelGGL(butterfly_kernel, dim3(blocks), dim3(256), 0, stream,
                       x, tw, bias, out);
}

// Round 4
// 282.928 us; speedup vs baseline: 2.4363x; 2.4363x over previous
//
#include <hip/hip_runtime.h>

// Butterfly (untied, increasing stride), batch=32768, n=1024, m=10 stages, nstack=1.
// One wave owns B_ROWS=4 rows in registers as 2 float2 row-pairs (v[2][16] = 64 VGPRs).
// Element->lane layout: e = r*256 + lane*4 + j  (r=0..3, j=0..3; 16 floats/lane/row).
//   strides 1,2    : intra-lane, position xor 1,2 (j bits)   -> float4 twiddle per pair
//   strides 4..128 : cross-lane, __shfl_xor masks 1,2,4,8,16,32 -> float2 twiddle per pos
//   strides 256,512: intra-lane, position xor 4,8 (r bits)   -> float4 twiddle per pair
//
// Stages are templated (compile-time STAGE) so every v[] index is static —
// runtime stage loop demoted v[] to LDS/scratch (rounds 1-2).
// __launch_bounds__(256,2): empirically the arch-VGPR cap behaves like
// 256/min_waves on this toolchain (r0:(256,2)->128, r3:(256,4)->64); we need
// ~110 regs, so min_waves=2 (cap 128) is required to avoid scratch spill.

constexpr int N = 1024;
constexpr int B_ROWS = 4;   // rows per wave
constexpr int WAVES = 4;    // waves per block (block = 256 threads)

template<int STAGE>
__device__ __forceinline__ void do_stage(float2 (&v)[2][16],
                                         const float* __restrict__ tw,
                                         const int lane)
{
    constexpr int s = 1 << STAGE;
    const float* tws = tw + (STAGE << 11);   // 512*4 floats per stage

    if constexpr (s >= 4 && s <= 128) {
        // cross-lane: partner is lane ^ (s>>2)
        constexpr int m = s >> 2;
        #pragma unroll
        for (int p = 0; p < 16; ++p) {
            const int e  = ((p >> 2) << 8) | (lane << 2) | (p & 3);
            const int i  = (e >> STAGE) & 1;
            const int pr = ((e >> (STAGE + 1)) << STAGE) | (e & (s - 1));
            const float2 tt = *(const float2*)(tws + pr * 4 + i * 2); // (t[i][0], t[i][1])
            const float tA = i ? tt.y : tt.x;   // t[i][i]
            const float tB = i ? tt.x : tt.y;   // t[i][1-i]
            #pragma unroll
            for (int q = 0; q < 2; ++q) {
                const float px = __shfl_xor(v[q][p].x, m, 64);
                const float py = __shfl_xor(v[q][p].y, m, 64);
                v[q][p].x = tA * v[q][p].x + tB * px;
                v[q][p].y = tA * v[q][p].y + tB * py;
            }
        }
    } else {
        // intra-lane: pair (p, p|pm); lower element has bit STAGE == 0
        constexpr int pm = (s == 1) ? 1 : (s == 2) ? 2 : (s == 256) ? 4 : 8;
        #pragma unroll
        for (int p = 0; p < 16; ++p) {
            if (p & pm) continue;
            const int p2 = p | pm;
            const int e  = ((p >> 2) << 8) | (lane << 2) | (p & 3);  // i==0 element
            const int pr = ((e >> (STAGE + 1)) << STAGE) | (e & (s - 1));
            const float4 t4 = *(const float4*)(tws + pr * 4); // t00 t01 t10 t11
            #pragma unroll
            for (int q = 0; q < 2; ++q) {
                const float2 a = v[q][p];
                const float2 b = v[q][p2];
                v[q][p].x  = t4.x * a.x + t4.y * b.x;
                v[q][p].y  = t4.x * a.y + t4.y * b.y;
                v[q][p2].x = t4.z * a.x + t4.w * b.x;
                v[q][p2].y = t4.z * a.y + t4.w * b.y;
            }
        }
    }
}

__global__ __launch_bounds__(256, 2)
void butterfly_kernel(const float* __restrict__ x,
                      const float* __restrict__ tw,    // [10][512][2][2]
                      const float* __restrict__ bias,  // [1024]
                      float* __restrict__ out)
{
    const int lane  = threadIdx.x & 63;
    const int waveg = blockIdx.x * WAVES + (threadIdx.x >> 6);
    const size_t row0 = (size_t)waveg * B_ROWS;

    float2 v[2][16];   // [row-pair q][position p], .x = row 2q, .y = row 2q+1

    // ---- load: coalesced float4 per row ----
    #pragma unroll
    for (int q = 0; q < 2; ++q) {
        const float* p0 = x + (row0 + 2 * q) * N + lane * 4;
        const float* p1 = p0 + N;
        #pragma unroll
        for (int r = 0; r < 4; ++r) {
            const float4 a = *(const float4*)(p0 + r * 256);
            const float4 b = *(const float4*)(p1 + r * 256);
            v[q][r * 4 + 0] = make_float2(a.x, b.x);
            v[q][r * 4 + 1] = make_float2(a.y, b.y);
            v[q][r * 4 + 2] = make_float2(a.z, b.z);
            v[q][r * 4 + 3] = make_float2(a.w, b.w);
        }
    }

    // ---- 10 butterfly stages, fully static ----
    do_stage<0>(v, tw, lane);
    do_stage<1>(v, tw, lane);
    do_stage<2>(v, tw, lane);
    do_stage<3>(v, tw, lane);
    do_stage<4>(v, tw, lane);
    do_stage<5>(v, tw, lane);
    do_stage<6>(v, tw, lane);
    do_stage<7>(v, tw, lane);
    do_stage<8>(v, tw, lane);
    do_stage<9>(v, tw, lane);

    // ---- store with bias ----
    #pragma unroll
    for (int q = 0; q < 2; ++q) {
        float* o0 = out + (row0 + 2 * q) * N + lane * 4;
        float* o1 = o0 + N;
        #pragma unroll
        for (int r = 0; r < 4; ++r) {
            const float4 bb = *(const float4*)(bias + r * 256 + lane * 4);
            float4 a, b;
            a.x = v[q][r * 4 + 0].x + bb.x;  b.x = v[q][r * 4 + 0].y + bb.x;
            a.y = v[q][r * 4 + 1].x + bb.y;  b.y = v[q][r * 4 + 1].y + bb.y;
            a.z = v[q][r * 4 + 2].x + bb.z;  b.z = v[q][r * 4 + 2].y + bb.z;
            a.w = v[q][r * 4 + 3].x + bb.w;  b.w = v[q][r * 4 + 3].y + bb.w;
            *(float4*)(o0 + r * 256) = a;
            *(float4*)(o1 + r * 256) = b;
        }
    }
}

extern "C" void kernel_launch(void* const* d_in, const int* in_sizes, int n_in,
                              void* d_out, int out_size, void* d_ws, size_t ws_size,
                              hipStream_t stream) {
    const float* x    = (const float*)d_in[0];   // [batch][1024]
    const float* tw   = (const float*)d_in[1];   // [1][10][512][2][2]
    const float* bias = (const float*)d_in[2];   // [1024]
    float* out        = (float*)d_out;

    const int batch = in_sizes[0] / N;           // 32768
    const int blocks = batch / (B_ROWS * WAVES); // 2048
    hipLaunchKernelGGL(butterfly_kernel, dim3(blocks), dim3(256), 0, stream,
                       x, tw, bias, out);
}